// Round 2
// baseline (220.682 us; speedup 1.0000x reference)
//
#include <hip/hip_runtime.h>
#include <stdint.h>

#define C_INPUTS 41024
#define C_KEFF   40960   // last 64 cols of W are zero -> skip exactly
#define C_L1     256
#define C_BATCH  2048
#define C_BK     32
#define C_MTILE  64
#define C_KSPLIT 8
#define C_KCHUNK (C_KEFF / C_KSPLIT)     // 5120
#define C_NITER  (C_KCHUNK / C_BK)       // 160
#define C_MBLOCKS 64
#define C_NKT    (C_KEFF / C_BK)         // 1280 k-tiles total
#define C_WTILE  (C_L1 * C_BK * 2)       // 16384 B  (bf16 W tile, fragment-major)
#define C_ATILE  (C_MTILE * C_BK * 2)    // 4096 B   (bf16 A tile, fragment-major)
#define C_BUF    (C_WTILE + C_ATILE)     // 20480 B
#define C_NBUF   3
#define LDS_TOTAL (C_NBUF * C_BUF)       // 61440 B -> 2 blocks/CU
#define WS_W_BYTES ((size_t)C_L1 * C_KEFF * 2)   // 20,971,520

typedef __attribute__((ext_vector_type(8))) short  short8;
typedef __attribute__((ext_vector_type(4))) float  f32x4;

typedef __attribute__((address_space(1))) const uint32_t g_as1_u32;
typedef __attribute__((address_space(3))) uint32_t      l_as3_u32;

__device__ __forceinline__ uint16_t bf16_rtne(float f) {
  uint32_t u = __builtin_bit_cast(uint32_t, f);
  u += 0x7fffu + ((u >> 16) & 1u);
  return (uint16_t)(u >> 16);
}

// ---------------------------------------------------------------------------
// Kernel 1: W [256, 41024] f32 -> bf16 workspace in FRAGMENT-MAJOR k-tiles.
// Tile kt (32 k's): elem(kt, f, l, j) = W[16f + (l&15)][kt*32 + (l>>4)*8 + j]
// f = 0..15 (16-col group), l = 0..63 (frag lane), j = 0..7.
// GEMM then global_load_lds's each wave's 4 KB linearly and ds_reads at
// region + lane*16 -> zero bank conflicts by construction.
// ---------------------------------------------------------------------------
__global__ __launch_bounds__(256) void k_convert_w(const float* __restrict__ W,
                                                   uint16_t* __restrict__ wsW) {
  const int kt = blockIdx.x;    // 0..1279
  const int t  = threadIdx.x;
  const int l  = t & 63;
  const int fb = t >> 6;        // 0..3
  const int rm = l & 15;
  const int kg = l >> 4;        // 0..3
  const int kcol = kt * C_BK + kg * 8;
  uint16_t* dst = wsW + (size_t)kt * (C_L1 * C_BK) + (size_t)l * 8;
#pragma unroll
  for (int q = 0; q < 4; ++q) {
    const int f = fb * 4 + q;
    const int row = f * 16 + rm;
    const float4* s = (const float4*)(W + (size_t)row * C_INPUTS + kcol);
    float4 x = s[0];
    float4 y = s[1];
    union { uint16_t h[8]; short8 v; } u;
    u.h[0] = bf16_rtne(x.x); u.h[1] = bf16_rtne(x.y);
    u.h[2] = bf16_rtne(x.z); u.h[3] = bf16_rtne(x.w);
    u.h[4] = bf16_rtne(y.x); u.h[5] = bf16_rtne(y.y);
    u.h[6] = bf16_rtne(y.z); u.h[7] = bf16_rtne(y.w);
    *(short8*)(dst + (size_t)f * 512) = u.v;
  }
}

// ---------------------------------------------------------------------------
// Kernel 2: main GEMM, 3-buffer / prefetch-distance-2 pipeline with counted
// vmcnt (never 0 in steady state). Block = (mb, ks): 64 rows x 256 cols over
// k-chunk 5120 (BK=32, 160 iters). 4 waves, wave owns 64x64 N-quadrant
// (4x4 frags of 16x16x32 bf16). W via global_load_lds (contiguous 1KB/wave),
// A via global->reg (2-deep)->cvt->ds_write (fragment-major, conflict-free).
// ---------------------------------------------------------------------------
__global__ __launch_bounds__(256, 2) void k_gemm(const float* __restrict__ w_in,
                                                 const float* __restrict__ b_in,
                                                 const uint16_t* __restrict__ wsW,
                                                 float* __restrict__ wsP) {
  extern __shared__ char smem[];
  const int bid  = blockIdx.x;
  const int ks   = bid & 7;     // XCD-affine k-split: per-XCD 2.6MB W chunk fits L2
  const int mb   = bid >> 3;    // 0..63
  const int tid  = threadIdx.x;
  const int wave = tid >> 6;
  const int lane = tid & 63;
  const int lrow = lane & 15;
  const int lg   = lane >> 4;

  const int k0 = ks * C_KCHUNK;
  const float* Abase = (mb < 32)
      ? (w_in + (size_t)mb * C_MTILE * C_INPUTS)
      : (b_in + (size_t)(mb - 32) * C_MTILE * C_INPUTS);

  // A staging: 4 threads per row, each loads 8 consecutive f32 (2 float4).
  const int ar = tid >> 2;   // row 0..63
  const int ac = tid & 3;    // k-subgroup (8 f32)
  const float* aptr = Abase + (size_t)ar * C_INPUTS + k0 + ac * 8;
  // A frag layout: [mi][l][8]; this thread's data lands at frag mi=ar>>4,
  // lane l = ac*16 + (ar&15) -> byte C_WTILE + mi*1024 + l*16 (a permutation
  // of lane*16 within each 1KB region -> conflict-free ds_write_b128).
  const int awoff = C_WTILE + ((ar >> 4) << 10) + ((ac * 16 + (ar & 15)) << 4);

  // W global source: per-thread, issue c covers frag f = wave*4 + c.
  const char* wg = (const char*)wsW + (size_t)(ks * C_NITER) * C_WTILE
                 + (size_t)wave * 4096 + (size_t)lane * 16;

  f32x4 acc[4][4];
#pragma unroll
  for (int i = 0; i < 4; ++i)
#pragma unroll
    for (int j = 0; j < 4; ++j) acc[i][j] = (f32x4){0.f, 0.f, 0.f, 0.f};

  float4 avA[2], avB[2];
  int cb = 0;  // current LDS buffer byte base

  // ---- prologue: W0->buf0, W1->buf1, A0->avA, A1->avB; cvt A0; full drain ----
  {
#pragma unroll
    for (int c = 0; c < 4; ++c) {
      __builtin_amdgcn_global_load_lds((g_as1_u32*)(wg + c * 1024),
                                       (l_as3_u32*)(smem + wave * 4096 + c * 1024), 16, 0, 0);
      __builtin_amdgcn_global_load_lds((g_as1_u32*)(wg + C_WTILE + c * 1024),
                                       (l_as3_u32*)(smem + C_BUF + wave * 4096 + c * 1024), 16, 0, 0);
    }
    const float4* p0 = (const float4*)aptr;
    avA[0] = p0[0]; avA[1] = p0[1];
    const float4* p1 = (const float4*)(aptr + C_BK);
    avB[0] = p1[0]; avB[1] = p1[1];
    union { uint16_t h[8]; short8 v; } u;
    u.h[0] = bf16_rtne(avA[0].x); u.h[1] = bf16_rtne(avA[0].y);
    u.h[2] = bf16_rtne(avA[0].z); u.h[3] = bf16_rtne(avA[0].w);
    u.h[4] = bf16_rtne(avA[1].x); u.h[5] = bf16_rtne(avA[1].y);
    u.h[6] = bf16_rtne(avA[1].z); u.h[7] = bf16_rtne(avA[1].w);
    *(short8*)(smem + awoff) = u.v;
    asm volatile("s_waitcnt vmcnt(0)" ::: "memory");  // once: everything resident
    asm volatile("s_waitcnt lgkmcnt(0)" ::: "memory");
    __builtin_amdgcn_s_barrier();
    __builtin_amdgcn_sched_barrier(0);
  }

  // Steady state at top of iter t: outstanding = A_{t+1}(2) + W_{t+1}(4) = 6.
  // Iter t issues A_{t+2}(2) + W_{t+2}(4); explicit vmcnt(6) before the
  // barrier keeps only iter-t's issues in flight -> W_{t+1}/A_{t+1} (issued a
  // full iteration ago) are proven drained, with zero fresh-load stalls.
#define GEMM_STEP(T, AVI, AVC) do {                                          \
    const bool pf = (T) + 2 < C_NITER;                                       \
    const int nb1 = (cb + C_BUF < LDS_TOTAL) ? cb + C_BUF : cb + C_BUF - LDS_TOTAL; \
    const int nb2 = (nb1 + C_BUF < LDS_TOTAL) ? nb1 + C_BUF : nb1 + C_BUF - LDS_TOTAL; \
    if (pf) {                                                                \
      const float4* p = (const float4*)(aptr + (size_t)((T) + 2) * C_BK);    \
      AVI[0] = p[0]; AVI[1] = p[1];                                          \
      const char* wsrc = wg + (size_t)((T) + 2) * C_WTILE;                   \
      char* wdst = smem + nb2 + wave * 4096;                                 \
      _Pragma("unroll")                                                      \
      for (int c = 0; c < 4; ++c)                                            \
        __builtin_amdgcn_global_load_lds((g_as1_u32*)(wsrc + c * 1024),      \
                                         (l_as3_u32*)(wdst + c * 1024), 16, 0, 0); \
    }                                                                        \
    {                                                                        \
      const char* ab = smem + cb;                                            \
      short8 af[4], bf[4];                                                   \
      _Pragma("unroll")                                                      \
      for (int mi = 0; mi < 4; ++mi)                                         \
        af[mi] = *(const short8*)(ab + C_WTILE + mi * 1024 + lane * 16);     \
      _Pragma("unroll")                                                      \
      for (int ni = 0; ni < 4; ++ni)                                         \
        bf[ni] = *(const short8*)(ab + wave * 4096 + ni * 1024 + lane * 16); \
      _Pragma("unroll")                                                      \
      for (int mi = 0; mi < 4; ++mi)                                         \
        _Pragma("unroll")                                                    \
        for (int ni = 0; ni < 4; ++ni)                                       \
          acc[mi][ni] = __builtin_amdgcn_mfma_f32_16x16x32_bf16(af[mi], bf[ni], acc[mi][ni], 0, 0, 0); \
    }                                                                        \
    if ((T) + 1 < C_NITER) {                                                 \
      union { uint16_t h[8]; short8 v; } u;                                  \
      u.h[0] = bf16_rtne(AVC[0].x); u.h[1] = bf16_rtne(AVC[0].y);            \
      u.h[2] = bf16_rtne(AVC[0].z); u.h[3] = bf16_rtne(AVC[0].w);            \
      u.h[4] = bf16_rtne(AVC[1].x); u.h[5] = bf16_rtne(AVC[1].y);            \
      u.h[6] = bf16_rtne(AVC[1].z); u.h[7] = bf16_rtne(AVC[1].w);            \
      *(short8*)(smem + nb1 + awoff) = u.v;                                  \
    }                                                                        \
    if (pf) { asm volatile("s_waitcnt vmcnt(6)" ::: "memory"); }             \
    else    { asm volatile("s_waitcnt vmcnt(0)" ::: "memory"); }             \
    asm volatile("s_waitcnt lgkmcnt(0)" ::: "memory");                       \
    __builtin_amdgcn_s_barrier();                                            \
    __builtin_amdgcn_sched_barrier(0);                                       \
    cb = nb1;                                                                \
  } while (0)

#pragma unroll 1
  for (int t = 0; t < C_NITER; t += 2) {
    GEMM_STEP(t,     avA, avB);   // issues A_{t+2}->avA, converts A_{t+1} (avB)
    GEMM_STEP(t + 1, avB, avA);   // issues A_{t+3}->avB, converts A_{t+2} (avA)
  }
#undef GEMM_STEP

  // ---- store partials: C/D layout col=lane&15, row=(lane>>4)*4+reg ----
  float* P = wsP + ((size_t)ks * 4096 + (size_t)mb * C_MTILE) * 256;
#pragma unroll
  for (int mi = 0; mi < 4; ++mi)
#pragma unroll
    for (int ni = 0; ni < 4; ++ni)
#pragma unroll
      for (int j = 0; j < 4; ++j) {
        const int rr = mi * 16 + lg * 4 + j;
        const int cc = wave * 64 + ni * 16 + lrow;
        P[(size_t)rr * 256 + cc] = acc[mi][ni][j];
      }
}

// ---------------------------------------------------------------------------
// Kernel 3: reduce 8 k-split partials, add bias, perspective mix, clamp.
// ---------------------------------------------------------------------------
__global__ __launch_bounds__(256) void k_reduce(const float* __restrict__ wsP,
                                                const float* __restrict__ us,
                                                const float* __restrict__ them,
                                                const float* __restrict__ bias,
                                                float* __restrict__ out) {
  const int r = blockIdx.x;    // 0..2047
  const int c = threadIdx.x;   // 0..255
  float wd = 0.f, bd = 0.f;
#pragma unroll
  for (int s = 0; s < C_KSPLIT; ++s) {
    wd += wsP[((size_t)s * 4096 + r) * 256 + c];
    bd += wsP[((size_t)s * 4096 + 2048 + r) * 256 + c];
  }
  const float bi = bias[c];
  const float w = wd + bi;
  const float b = bd + bi;
  const float u = us[r];
  const float t = them[r];
  float o1 = u * w + t * b;
  float o2 = u * b + t * w;
  o1 = fminf(fmaxf(o1, 0.f), 1.f);
  o2 = fminf(fmaxf(o2, 0.f), 1.f);
  out[(size_t)r * 512 + c]       = o1;
  out[(size_t)r * 512 + 256 + c] = o2;
}

extern "C" void kernel_launch(void* const* d_in, const int* in_sizes, int n_in,
                              void* d_out, int out_size, void* d_ws, size_t ws_size,
                              hipStream_t stream) {
  const float* us   = (const float*)d_in[0];
  const float* them = (const float*)d_in[1];
  const float* w_in = (const float*)d_in[2];
  const float* b_in = (const float*)d_in[3];
  const float* W    = (const float*)d_in[4];
  const float* bias = (const float*)d_in[5];
  float* out = (float*)d_out;

  uint16_t* wsW = (uint16_t*)d_ws;
  float*    wsP = (float*)((char*)d_ws + WS_W_BYTES);

  k_convert_w<<<C_NKT, 256, 0, stream>>>(W, wsW);
  k_gemm<<<C_MBLOCKS * C_KSPLIT, 256, LDS_TOTAL, stream>>>(w_in, b_in, wsW, wsP);
  k_reduce<<<C_BATCH, 256, 0, stream>>>(wsP, us, them, bias, out);
}